// Round 8
// baseline (95.953 us; speedup 1.0000x reference)
//
#include <hip/hip_runtime.h>

#define N_NODES 100000
#define E_EDGES 2000000
#define SPLIT_E 1800000   // top 10%: 400k touches, P(node untouched) ~ e^-4 ~ 1.8%
#define CIN 16
#define EXH_FLOW 4.0f     // 0.0001 * 40000
#define TOP_E (E_EDGES - SPLIT_E)
#define NBITS_WORDS ((N_NODES + 31) / 32)   // 3125 words = 12.5 KB

// origin_data: (N, 8, 3) f32; last timestep at n*24 + {21,22,23} = {conc, people, size}

// K1: node init + table init (in-kernel stores; memset nodes regressed in R6).
__global__ void init_nodes_kernel(const float* __restrict__ origin,
                                  float* __restrict__ out,
                                  int* __restrict__ max_ord,
                                  float* __restrict__ conc_c,
                                  float* __restrict__ rsize_c,
                                  unsigned int* __restrict__ settled_bits) {
    int n = blockIdx.x * blockDim.x + threadIdx.x;
    if (n >= N_NODES) return;
    size_t base = (size_t)n * 24;
    float conc   = origin[base + 21];
    float people = origin[base + 22];
    float size   = origin[base + 23];
    float rs = 1.0f / size;
    out[n] = conc + EXH_FLOW * people * rs;
    conc_c[n]  = conc;
    rsize_c[n] = rs;
    max_ord[n] = -1;
    if (n < NBITS_WORDS) settled_bits[n] = 0u;
}

// K2: top chunk — pure atomics (values unsettled here; R2 lesson) + mark
// settled bit: top orders >= 2*SPLIT_E dominate all lower orders, so these
// nodes' maxes are FINAL after this dispatch. atomicOr result unused ->
// fire-and-forget (non-returning atomic).
__global__ void scatter_top_kernel(const int* __restrict__ src,
                                   const int* __restrict__ dst,
                                   int* __restrict__ max_ord,
                                   unsigned int* __restrict__ settled_bits) {
    int i = blockIdx.x * blockDim.x + threadIdx.x;
    int e = SPLIT_E + i;
    if (e >= E_EDGES) return;
    int s = src[e], d = dst[e];
    if (s != d) {
        atomicMax(&max_ord[s], 2 * e);
        atomicMax(&max_ord[d], 2 * e + 1);
        atomicOr(&settled_bits[s >> 5], 1u << (s & 31));
        atomicOr(&settled_bits[d >> 5], 1u << (d & 31));
    }
}

// K3: R5's measured-best fused structure — coalesced x-stream (4 lanes/edge,
// one float4 each, shfl reduce), leader lane (q==0) does flow store + scatter.
// Pre-check target is now a 12.5 KB IMMUTABLE bitmap (196 cache lines):
// read-only here -> stays hot in L1/L2 despite the x-stream's eviction
// pressure (R7 lesson: the 100 KB byte-map thrashed under co-residency).
// ~66k firing atomics hit a different array (max_ord).
__global__ void fused_flow_scatter_kernel(const float4* __restrict__ xv,
                                          const float* __restrict__ w,
                                          const float* __restrict__ b,
                                          const int* __restrict__ src,
                                          const int* __restrict__ dst,
                                          const unsigned int* __restrict__ settled_bits,
                                          float* __restrict__ flow,
                                          int* __restrict__ max_ord) {
    int tid = blockIdx.x * blockDim.x + threadIdx.x;   // over E*4 = 8M
    if (tid >= E_EDGES * 4) return;
    int q = tid & 3;
    int e = tid >> 2;
    float4 v  = xv[tid];                 // consecutive lanes -> consecutive 16B
    float4 wq = ((const float4*)w)[q];   // 64B total, L1 broadcast
    float p = v.x * wq.x + v.y * wq.y + v.z * wq.z + v.w * wq.w;
    p += __shfl_xor(p, 1);
    p += __shfl_xor(p, 2);
    if (q == 0) {
        flow[e] = p + b[0];              // 16 lanes/wave, contiguous 64B
        int s = src[e], d = dst[e];      // 16 lanes -> one 64B line each
        if (s != d) {
            unsigned int ws = settled_bits[s >> 5];
            if (!((ws >> (s & 31)) & 1u))
                atomicMax(&max_ord[s], 2 * e);
            unsigned int wd = settled_bits[d >> 5];
            if (!((wd >> (d & 31)) & 1u))
                atomicMax(&max_ord[d], 2 * e + 1);
        }
    }
}

// K4: per-node finalize — decode winning occurrence, gather its value.
__global__ void finalize_kernel(const int* __restrict__ src,
                                const float* __restrict__ flow,
                                const int* __restrict__ max_ord,
                                const float* __restrict__ conc_c,
                                const float* __restrict__ rsize_c,
                                float* __restrict__ out) {
    int n = blockIdx.x * blockDim.x + threadIdx.x;
    if (n >= N_NODES) return;
    int o = max_ord[n];
    if (o < 0) return;
    int e = o >> 1;
    float val = flow[e];
    float v;
    if ((o & 1) == 0) {
        v = val * conc_c[n] * rsize_c[n];            // src-side: src[e]==n
    } else {
        int s = src[e];
        v = val * conc_c[s] * rsize_c[n];            // dst-side
    }
    out[n] += v;
}

extern "C" void kernel_launch(void* const* d_in, const int* in_sizes, int n_in,
                              void* d_out, int out_size, void* d_ws, size_t ws_size,
                              hipStream_t stream) {
    const float* origin = (const float*)d_in[0];   // (N, 8, 3)
    const float* x      = (const float*)d_in[1];   // (E, 1, 16)
    const float* conv_w = (const float*)d_in[2];   // (1, 16, 1, 1)
    const float* conv_b = (const float*)d_in[3];   // (1,)
    const int*   eidx   = (const int*)d_in[4];     // (2, E)
    const int* src = eidx;
    const int* dst = eidx + E_EDGES;

    float* out  = (float*)d_out;          // [0, N): result; [N, N+E): flow
    float* flow = out + N_NODES;

    int*          max_ord      = (int*)d_ws;                           // 400 KB
    float*        conc_c       = (float*)((char*)d_ws + 1 * 400 * 1024);
    float*        rsize_c      = (float*)((char*)d_ws + 2 * 400 * 1024);
    unsigned int* settled_bits = (unsigned int*)((char*)d_ws + 3 * 400 * 1024); // 12.5 KB

    const int BLK = 256;
    init_nodes_kernel<<<(N_NODES + BLK - 1) / BLK, BLK, 0, stream>>>(
        origin, out, max_ord, conc_c, rsize_c, settled_bits);
    scatter_top_kernel<<<(TOP_E + BLK - 1) / BLK, BLK, 0, stream>>>(
        src, dst, max_ord, settled_bits);
    fused_flow_scatter_kernel<<<((E_EDGES * 4) + BLK - 1) / BLK, BLK, 0, stream>>>(
        (const float4*)x, conv_w, conv_b, src, dst, settled_bits, flow, max_ord);
    finalize_kernel<<<(N_NODES + BLK - 1) / BLK, BLK, 0, stream>>>(
        src, flow, max_ord, conc_c, rsize_c, out);
}

// Round 9
// 65.301 us; speedup vs baseline: 1.4694x; 1.4694x over previous
//
#include <hip/hip_runtime.h>

#define N_NODES 100000
#define E_EDGES 2000000
#define SPLIT_E 1800000   // top 10%: 400k touches, P(node untouched) ~ e^-4 ~ 1.8%
#define CIN 16
#define EXH_FLOW 4.0f     // 0.0001 * 40000
#define TOP_E (E_EDGES - SPLIT_E)

#define UNROLL 4
#define ECHUNK (E_EDGES / UNROLL)          // 500000 edges per chunk
#define QTHREADS (E_EDGES * 4 / UNROLL)    // 2M threads, 4 lanes/edge, 4 edges/thread

// origin_data: (N, 8, 3) f32; last timestep at n*24 + {21,22,23} = {conc, people, size}

// K1: node init + table init (in-kernel stores; memset nodes regressed R6,
// bitmap atomicOr marking regressed R8 — keep R5's byte-map + plain stores).
__global__ void init_nodes_kernel(const float* __restrict__ origin,
                                  float* __restrict__ out,
                                  int* __restrict__ max_ord,
                                  float* __restrict__ conc_c,
                                  float* __restrict__ rsize_c,
                                  unsigned char* __restrict__ settled) {
    int n = blockIdx.x * blockDim.x + threadIdx.x;
    if (n >= N_NODES) return;
    size_t base = (size_t)n * 24;
    float conc   = origin[base + 21];
    float people = origin[base + 22];
    float size   = origin[base + 23];
    float rs = 1.0f / size;
    out[n] = conc + EXH_FLOW * people * rs;
    conc_c[n]  = conc;
    rsize_c[n] = rs;
    max_ord[n] = -1;
    settled[n] = 0;
}

// K2: top chunk — pure atomics on max_ord (values unsettled here; R2 lesson)
// + settled byte-map marking via PLAIN stores (same-value races benign;
// atomicOr-to-bitmap serialized per word and regressed — R8 lesson).
// Top orders >= 2*SPLIT_E dominate all lower orders -> marks are FINAL.
__global__ void scatter_top_kernel(const int* __restrict__ src,
                                   const int* __restrict__ dst,
                                   int* __restrict__ max_ord,
                                   unsigned char* __restrict__ settled) {
    int i = blockIdx.x * blockDim.x + threadIdx.x;
    int e = SPLIT_E + i;
    if (e >= E_EDGES) return;
    int s = src[e], d = dst[e];
    if (s != d) {
        atomicMax(&max_ord[s], 2 * e);
        atomicMax(&max_ord[d], 2 * e + 1);
        settled[s] = 1;
        settled[d] = 1;
    }
}

// K3: R5's measured-best fused structure + x4 MLP. Each thread keeps its
// quarter-role q but covers 4 edges strided by ECHUNK; the 4 float4 loads
// are independent and issue together (4x outstanding requests per lane —
// R7's cache-resident rerun showed the 1-load version is request-limited,
// not BW-limited). Coalescing preserved: consecutive lanes -> consecutive
// 16B within each k. Leader (q==0) stores flow (16/wave -> 64B contiguous
// per k) and does the settled-precheck scatter (immutable 100 KB byte-map,
// read-only here -> L2-hot; ~66k firing atomics hit max_ord, not the map).
__global__ void fused_flow_scatter_kernel(const float4* __restrict__ xv,
                                          const float* __restrict__ w,
                                          const float* __restrict__ b,
                                          const int* __restrict__ src,
                                          const int* __restrict__ dst,
                                          const unsigned char* __restrict__ settled,
                                          float* __restrict__ flow,
                                          int* __restrict__ max_ord) {
    int tid = blockIdx.x * blockDim.x + threadIdx.x;   // [0, 2M)
    if (tid >= QTHREADS) return;
    int q  = tid & 3;
    int e0 = tid >> 2;                    // [0, 500k)
    float4 wq = ((const float4*)w)[q];    // 64B total, L1 broadcast
    float bias = b[0];

    // 4 independent coalesced loads, issued before any use.
    float4 v0 = xv[tid + 0 * QTHREADS];
    float4 v1 = xv[tid + 1 * QTHREADS];
    float4 v2 = xv[tid + 2 * QTHREADS];
    float4 v3 = xv[tid + 3 * QTHREADS];

    float p0 = v0.x * wq.x + v0.y * wq.y + v0.z * wq.z + v0.w * wq.w;
    float p1 = v1.x * wq.x + v1.y * wq.y + v1.z * wq.z + v1.w * wq.w;
    float p2 = v2.x * wq.x + v2.y * wq.y + v2.z * wq.z + v2.w * wq.w;
    float p3 = v3.x * wq.x + v3.y * wq.y + v3.z * wq.z + v3.w * wq.w;

    p0 += __shfl_xor(p0, 1);  p0 += __shfl_xor(p0, 2);
    p1 += __shfl_xor(p1, 1);  p1 += __shfl_xor(p1, 2);
    p2 += __shfl_xor(p2, 1);  p2 += __shfl_xor(p2, 2);
    p3 += __shfl_xor(p3, 1);  p3 += __shfl_xor(p3, 2);

    if (q == 0) {
        int ea = e0, eb = e0 + ECHUNK, ec = e0 + 2 * ECHUNK, ed = e0 + 3 * ECHUNK;
        flow[ea] = p0 + bias;
        flow[eb] = p1 + bias;
        flow[ec] = p2 + bias;
        flow[ed] = p3 + bias;
        int sa = src[ea], da = dst[ea];
        int sb = src[eb], db = dst[eb];
        int sc = src[ec], dc = dst[ec];
        int sd = src[ed], dd = dst[ed];
#define SCAT(EE, SS, DD)                                                  \
        if ((SS) != (DD)) {                                               \
            if (!settled[SS]) atomicMax(&max_ord[SS], 2 * (EE));          \
            if (!settled[DD]) atomicMax(&max_ord[DD], 2 * (EE) + 1);      \
        }
        SCAT(ea, sa, da)
        SCAT(eb, sb, db)
        SCAT(ec, sc, dc)
        SCAT(ed, sd, dd)
#undef SCAT
    }
}

// K4: per-node finalize — decode winning occurrence, gather its value.
__global__ void finalize_kernel(const int* __restrict__ src,
                                const float* __restrict__ flow,
                                const int* __restrict__ max_ord,
                                const float* __restrict__ conc_c,
                                const float* __restrict__ rsize_c,
                                float* __restrict__ out) {
    int n = blockIdx.x * blockDim.x + threadIdx.x;
    if (n >= N_NODES) return;
    int o = max_ord[n];
    if (o < 0) return;
    int e = o >> 1;
    float val = flow[e];
    float v;
    if ((o & 1) == 0) {
        v = val * conc_c[n] * rsize_c[n];            // src-side: src[e]==n
    } else {
        int s = src[e];
        v = val * conc_c[s] * rsize_c[n];            // dst-side
    }
    out[n] += v;
}

extern "C" void kernel_launch(void* const* d_in, const int* in_sizes, int n_in,
                              void* d_out, int out_size, void* d_ws, size_t ws_size,
                              hipStream_t stream) {
    const float* origin = (const float*)d_in[0];   // (N, 8, 3)
    const float* x      = (const float*)d_in[1];   // (E, 1, 16)
    const float* conv_w = (const float*)d_in[2];   // (1, 16, 1, 1)
    const float* conv_b = (const float*)d_in[3];   // (1,)
    const int*   eidx   = (const int*)d_in[4];     // (2, E)
    const int* src = eidx;
    const int* dst = eidx + E_EDGES;

    float* out  = (float*)d_out;          // [0, N): result; [N, N+E): flow
    float* flow = out + N_NODES;

    int*           max_ord = (int*)d_ws;                           // 400 KB
    float*         conc_c  = (float*)((char*)d_ws + 1 * 400 * 1024);
    float*         rsize_c = (float*)((char*)d_ws + 2 * 400 * 1024);
    unsigned char* settled = (unsigned char*)((char*)d_ws + 3 * 400 * 1024); // 100 KB

    const int BLK = 256;
    init_nodes_kernel<<<(N_NODES + BLK - 1) / BLK, BLK, 0, stream>>>(
        origin, out, max_ord, conc_c, rsize_c, settled);
    scatter_top_kernel<<<(TOP_E + BLK - 1) / BLK, BLK, 0, stream>>>(
        src, dst, max_ord, settled);
    fused_flow_scatter_kernel<<<(QTHREADS + BLK - 1) / BLK, BLK, 0, stream>>>(
        (const float4*)x, conv_w, conv_b, src, dst, settled, flow, max_ord);
    finalize_kernel<<<(N_NODES + BLK - 1) / BLK, BLK, 0, stream>>>(
        src, flow, max_ord, conc_c, rsize_c, out);
}